// Round 14
// baseline (32.269 us; speedup 1.0000x reference)
//
#include <hip/hip_runtime.h>

#define CPN  1000
#define NAUX (CPN + 3)   // 1003 aux points / knots (idx 0..1002)
#define M    4096        // uniform resample intervals
#define EPSF 1e-7f

// unpack low/high f16 of u32 -> f32
static __device__ __forceinline__ float h2f_lo(unsigned int u) {
    unsigned short us = (unsigned short)u;
    __fp16 h = *reinterpret_cast<__fp16*>(&us);
    return (float)h;
}
static __device__ __forceinline__ float h2f_hi(unsigned int u) {
    unsigned short us = (unsigned short)(u >> 16);
    __fp16 h = *reinterpret_cast<__fp16*>(&us);
    return (float)h;
}
// pack two f32 -> u32 of two f16, round-to-nearest (v_cvt_f16_f32)
static __device__ __forceinline__ unsigned int pk2h_rtn(float a, float b) {
    __fp16 ha = (__fp16)a, hb = (__fp16)b;
    unsigned short ua = *reinterpret_cast<unsigned short*>(&ha);
    unsigned short ub = *reinterpret_cast<unsigned short*>(&hb);
    return (unsigned int)ua | ((unsigned int)ub << 16);
}

// ---------------------------------------------------------------------------
// Setup: identical to R13 (passed, absmax 0.25 — resample is accuracy-free).
// ---------------------------------------------------------------------------
__global__ __launch_bounds__(1024)
void spline_setup(const float* __restrict__ cps,
                  uint4* __restrict__ g_rec,    // M x 16B f16 interval records
                  float* __restrict__ g_meta)   // {lo, hi, w, inv_w}
{
    __shared__ float sax[NAUX];
    __shared__ float say[NAUX];
    __shared__ float skn[NAUX + 1];
    __shared__ float wsum[16];
    __shared__ float segc[8 * CPN];   // 32 KB exact segment coeffs
    const int tid = threadIdx.x;

    const float c0x = cps[0],         c0y = cps[1];
    const float c1x = cps[2],         c1y = cps[3];
    const float cLx = cps[2*(CPN-1)], cLy = cps[2*(CPN-1)+1];
    const float dx01 = c0x - c1x, dy01 = c0y - c1y;
    const float dxL  = c0x - cLx, dyL  = c0y - cLy;
    const float l01   = sqrtf(dx01*dx01 + dy01*dy01 + EPSF);
    const float llast = sqrtf(dxL*dxL   + dyL*dyL   + EPSF);

    if (tid < CPN) { sax[tid+1] = cps[2*tid]; say[tid+1] = cps[2*tid+1]; }
    if (tid == 0) {
        sax[0]     = c0x - (l01/llast) * dxL;
        say[0]     = c0y - (l01/llast) * dyL;
        sax[CPN+1] = c0x;  say[CPN+1] = c0y;
        sax[CPN+2] = c0x + (llast/l01) * (c1x - c0x);
        say[CPN+2] = c0y + (llast/l01) * (c1y - c0y);
    }
    __syncthreads();

    float v = 0.f;
    if (tid < NAUX - 1) {
        const float dx = sax[tid+1] - sax[tid];
        const float dy = say[tid+1] - say[tid];
        v = sqrtf(sqrtf(dx*dx + dy*dy));
    }
    #pragma unroll
    for (int off = 1; off < 64; off <<= 1) {
        const float w_ = __shfl_up(v, off, 64);
        if ((tid & 63) >= off) v += w_;
    }
    if ((tid & 63) == 63) wsum[tid >> 6] = v;
    __syncthreads();
    if (tid < 16) {
        float x = wsum[tid];
        #pragma unroll
        for (int off = 1; off < 16; off <<= 1) {
            const float w_ = __shfl_up(x, off, 16);
            if (tid >= off) x += w_;
        }
        wsum[tid] = x;
    }
    __syncthreads();
    const float incl = v + ((tid >= 64) ? wsum[(tid >> 6) - 1] : 0.f);

    if (tid == 0)       { skn[0] = 0.f; skn[NAUX] = 1e30f; }
    if (tid < NAUX - 1) { skn[tid+1] = incl; }
    __syncthreads();

    // exact per-segment cubics in u = t - skn[sg]  (verified R6-R13)
    if (tid < CPN) {
        const int sg = tid + 1;
        const float t0 = skn[sg-1], t1 = skn[sg], t2 = skn[sg+1], t3 = skn[sg+2];
        const float A = t1 - t0, B = t2 - t1, C = t3 - t2;
        const float r01 = 1.0f / A;
        const float r12 = 1.0f / B;
        const float r23 = 1.0f / C;
        const float r02 = 1.0f / (A + B);
        const float r13 = 1.0f / (B + C);
        const float C3  = B + C;

        const float P0x = sax[sg-1], P0y = say[sg-1];
        const float P1x = sax[sg],   P1y = say[sg];
        const float P2x = sax[sg+1], P2y = say[sg+1];
        const float P3x = sax[sg+2], P3y = say[sg+2];

        const float L01_1x = (P1x - P0x) * r01, L01_1y = (P1y - P0y) * r01;
        const float L12_1x = (P2x - P1x) * r12, L12_1y = (P2y - P1y) * r12;
        const float L23_0x = ((B + C) * P2x - B * P3x) * r23;
        const float L23_0y = ((B + C) * P2y - B * P3y) * r23;
        const float L23_1x = (P3x - P2x) * r23, L23_1y = (P3y - P2y) * r23;

        const float Q012_0x = (B * P1x + A * P1x) * r02;
        const float Q012_0y = (B * P1y + A * P1y) * r02;
        const float Q012_1x = (B * L01_1x - P1x + A * L12_1x + P1x) * r02;
        const float Q012_1y = (B * L01_1y - P1y + A * L12_1y + P1y) * r02;
        const float Q012_2x = (L12_1x - L01_1x) * r02;
        const float Q012_2y = (L12_1y - L01_1y) * r02;

        const float Q123_0x = C3 * P1x * r13;
        const float Q123_0y = C3 * P1y * r13;
        const float Q123_1x = (C3 * L12_1x - P1x + L23_0x) * r13;
        const float Q123_1y = (C3 * L12_1y - P1y + L23_0y) * r13;
        const float Q123_2x = (L23_1x - L12_1x) * r13;
        const float Q123_2y = (L23_1y - L12_1y) * r13;

        float* c = &segc[(size_t)tid * 8];
        c[0] = B * Q012_0x * r12;
        c[1] = (B * Q012_1x - Q012_0x + Q123_0x) * r12;
        c[2] = (B * Q012_2x - Q012_1x + Q123_1x) * r12;
        c[3] = (Q123_2x - Q012_2x) * r12;
        c[4] = B * Q012_0y * r12;
        c[5] = (B * Q012_1y - Q012_0y + Q123_0y) * r12;
        c[6] = (B * Q012_2y - Q012_1y + Q123_1y) * r12;
        c[7] = (Q123_2y - Q012_2y) * r12;
    }
    __syncthreads();

    const float lo = skn[1];
    const float hi = skn[CPN + 1];
    const float w  = (hi - lo) / (float)M;
    const float iw = (float)M / (hi - lo);

    if (tid == 0) {
        g_meta[0] = lo; g_meta[1] = hi; g_meta[2] = w; g_meta[3] = iw;
    }

    // Hermite resample: per interval i, true (f, f') at both endpoints
    for (int i = tid; i < M; i += 1024) {
        float f[2][2], d[2][2];   // [endpoint][axis]
        #pragma unroll
        for (int ep = 0; ep < 2; ++ep) {
            const float x = lo + (float)(i + ep) * w;
            int l = 0, h = 1003;
            #pragma unroll
            for (int it = 0; it < 10; ++it) {
                const int mid = (l + h) >> 1;
                const bool cnd = (skn[mid] <= x);
                l = cnd ? mid : l;
                h = cnd ? h : mid;
            }
            int s = l < 1 ? 1 : (l > CPN ? CPN : l);
            const float u = x - skn[s];
            const float* c = &segc[(size_t)(s - 1) * 8];
            f[ep][0] = fmaf(fmaf(fmaf(c[3], u, c[2]), u, c[1]), u, c[0]);
            d[ep][0] = fmaf(fmaf(3.0f * c[3], u, 2.0f * c[2]), u, c[1]);
            f[ep][1] = fmaf(fmaf(fmaf(c[7], u, c[6]), u, c[5]), u, c[4]);
            d[ep][1] = fmaf(fmaf(3.0f * c[7], u, 2.0f * c[6]), u, c[5]);
        }
        // Hermite -> power basis on [0,w]
        float cc[4][2];
        #pragma unroll
        for (int ax = 0; ax < 2; ++ax) {
            const float f0 = f[0][ax], f1 = f[1][ax];
            const float d0 = d[0][ax], d1 = d[1][ax];
            const float iwv = 1.0f / w;
            const float D = (f1 - f0) * iwv;
            cc[0][ax] = f0;
            cc[1][ax] = d0;
            cc[2][ax] = (3.0f * D - 2.0f * d0 - d1) * iwv;
            cc[3][ax] = (d0 + d1 - 2.0f * D) * iwv * iwv;
        }
        uint4 r;
        r.x = pk2h_rtn(cc[0][0], cc[0][1]);
        r.y = pk2h_rtn(cc[1][0], cc[1][1]);
        r.z = pk2h_rtn(cc[2][0], cc[2][1]);
        r.w = pk2h_rtn(cc[3][0], cc[3][1]);
        g_rec[i] = r;
    }
}

// ---------------------------------------------------------------------------
// Eval: 512 blocks x 1024 thr, 64KB LDS -> 2 blocks/CU (32 waves/CU).
// FINE-GRAINED grid-stride loop: 8 short trips of ONE pair each, so waves
// drift out of phase and HBM/LDS/VALU pipes overlap instead of serializing
// (R13 post-mortem: 2 fat iterations => pipe-SUM runtime).
// Per query: one b128 LDS gather + 2 Horners. Coalesced float2/float4 I/O.
// ---------------------------------------------------------------------------
__global__ __launch_bounds__(1024, 8)
void spline_eval(const float* __restrict__ tq,
                 const uint4* __restrict__ g_rec,
                 const float* __restrict__ g_meta,
                 float* __restrict__ out,   // n*2 floats
                 int n)
{
    __shared__ __align__(16) uint4 s_rec[M];   // 64 KB exactly
    const int tid = threadIdx.x;

    for (int i = tid; i < M; i += 1024) s_rec[i] = g_rec[i];

    const float lo    = g_meta[0];
    const float w     = g_meta[2];
    const float inv_w = g_meta[3];
    __syncthreads();

    const int gid = blockIdx.x * 1024 + tid;
    const int T   = gridDim.x * 1024;    // total threads (524288)
    const int P   = n >> 1;              // query pairs (4194304)

    const float2* tq2  = (const float2*)tq;
    float4*       out4 = (float4*)out;

    for (int p = gid; p < P; p += T) {   // 8 short trips
        const float2 t2 = tq2[p];        // coalesced 8B/lane

        int b0 = (int)((t2.x - lo) * inv_w);
        b0 = b0 < 0 ? 0 : (b0 > M - 1 ? M - 1 : b0);
        int b1 = (int)((t2.y - lo) * inv_w);
        b1 = b1 < 0 ? 0 : (b1 > M - 1 ? M - 1 : b1);

        const uint4 r0 = s_rec[b0];      // 2 independent gathers in flight
        const uint4 r1 = s_rec[b1];

        const float u0 = t2.x - fmaf((float)b0, w, lo);
        const float u1 = t2.y - fmaf((float)b1, w, lo);

        const float x0 = fmaf(fmaf(fmaf(h2f_lo(r0.w), u0, h2f_lo(r0.z)), u0, h2f_lo(r0.y)), u0, h2f_lo(r0.x));
        const float y0 = fmaf(fmaf(fmaf(h2f_hi(r0.w), u0, h2f_hi(r0.z)), u0, h2f_hi(r0.y)), u0, h2f_hi(r0.x));
        const float x1 = fmaf(fmaf(fmaf(h2f_lo(r1.w), u1, h2f_lo(r1.z)), u1, h2f_lo(r1.y)), u1, h2f_lo(r1.x));
        const float y1 = fmaf(fmaf(fmaf(h2f_hi(r1.w), u1, h2f_hi(r1.z)), u1, h2f_hi(r1.y)), u1, h2f_hi(r1.x));

        out4[p] = make_float4(x0, y0, x1, y1);   // coalesced 16B/lane
    }

    // tail (n odd) — not hit for N=8388608
    if ((n & 1) && gid == 0) {
        const int q = n - 1;
        const float t = tq[q];
        int b = (int)((t - lo) * inv_w);
        b = b < 0 ? 0 : (b > M - 1 ? M - 1 : b);
        const float u = t - fmaf((float)b, w, lo);
        const uint4 r = s_rec[b];
        out[2*q]     = fmaf(fmaf(fmaf(h2f_lo(r.w), u, h2f_lo(r.z)), u, h2f_lo(r.y)), u, h2f_lo(r.x));
        out[2*q + 1] = fmaf(fmaf(fmaf(h2f_hi(r.w), u, h2f_hi(r.z)), u, h2f_hi(r.y)), u, h2f_hi(r.x));
    }
}

extern "C" void kernel_launch(void* const* d_in, const int* in_sizes, int n_in,
                              void* d_out, int out_size, void* d_ws, size_t ws_size,
                              hipStream_t stream) {
    const float* cps = (const float*)d_in[0];
    const float* tq  = (const float*)d_in[1];
    float* out       = (float*)d_out;
    const int n      = in_sizes[1];

    // ws layout (bytes): [0, 65536) rec 16B x 4096 | [65536, 65552) meta
    uint4* g_rec  = (uint4*)d_ws;
    float* g_meta = (float*)((char*)d_ws + 65536);

    spline_setup<<<1, 1024, 0, stream>>>(cps, g_rec, g_meta);

    const int blocks = 512;   // 2 blocks/CU x 256 CUs, 32 waves/CU
    spline_eval<<<blocks, 1024, 0, stream>>>(tq, g_rec, g_meta, out, n);
}

// Round 15
// 27.424 us; speedup vs baseline: 1.1767x; 1.1767x over previous
//
#include <hip/hip_runtime.h>

#define CPN  1000
#define NAUX (CPN + 3)   // 1003 aux points / knots (idx 0..1002)
#define NB   1024        // LUT buckets (16B self-contained, <=5 knots branchless)
#define EPSF 1e-7f

typedef __fp16 half2v __attribute__((ext_vector_type(2)));
typedef float  f32x4  __attribute__((ext_vector_type(4)));

// pack two f32 -> u32 holding two f16 (v_cvt_pkrtz_f16_f32)
static __device__ __forceinline__ unsigned int pk2h(float a, float b) {
    half2v h = __builtin_amdgcn_cvt_pkrtz(a, b);
    return *reinterpret_cast<unsigned int*>(&h);
}
// unpack low/high f16 of u32 -> f32
static __device__ __forceinline__ float h2f_lo(unsigned int u) {
    unsigned short us = (unsigned short)u;
    __fp16 h = *reinterpret_cast<__fp16*>(&us);
    return (float)h;
}
static __device__ __forceinline__ float h2f_hi(unsigned int u) {
    unsigned short us = (unsigned short)(u >> 16);
    __fp16 h = *reinterpret_cast<__fp16*>(&us);
    return (float)h;
}
// full-line-coalesced nontemporal store (wave-contiguous 16B/lane)
static __device__ __forceinline__ void nt_store4(float* p, float a, float b, float c, float d) {
    f32x4 v = {a, b, c, d};
    __builtin_nontemporal_store(v, (f32x4*)p);
}

// ---------------------------------------------------------------------------
// Setup: identical to R11/R12 (passed, absmax 0.25).
// ---------------------------------------------------------------------------
__global__ __launch_bounds__(1024)
void spline_setup(const float* __restrict__ cps,
                  float* __restrict__ g_kn,       // 1024 floats (use 1004)
                  uint4* __restrict__ g_rec,      // 1000 x 16B f16 records
                  uint4* __restrict__ g_lut)      // NB x 16B entries
{
    __shared__ float sax[NAUX];
    __shared__ float say[NAUX];
    __shared__ float skn[NAUX + 1];
    __shared__ float wsum[16];
    const int tid = threadIdx.x;

    const float c0x = cps[0],         c0y = cps[1];
    const float c1x = cps[2],         c1y = cps[3];
    const float cLx = cps[2*(CPN-1)], cLy = cps[2*(CPN-1)+1];
    const float dx01 = c0x - c1x, dy01 = c0y - c1y;
    const float dxL  = c0x - cLx, dyL  = c0y - cLy;
    const float l01   = sqrtf(dx01*dx01 + dy01*dy01 + EPSF);
    const float llast = sqrtf(dxL*dxL   + dyL*dyL   + EPSF);

    if (tid < CPN) { sax[tid+1] = cps[2*tid]; say[tid+1] = cps[2*tid+1]; }
    if (tid == 0) {
        sax[0]     = c0x - (l01/llast) * dxL;
        say[0]     = c0y - (l01/llast) * dyL;
        sax[CPN+1] = c0x;  say[CPN+1] = c0y;
        sax[CPN+2] = c0x + (llast/l01) * (c1x - c0x);
        say[CPN+2] = c0y + (llast/l01) * (c1y - c0y);
    }
    __syncthreads();

    float v = 0.f;
    if (tid < NAUX - 1) {
        const float dx = sax[tid+1] - sax[tid];
        const float dy = say[tid+1] - say[tid];
        v = sqrtf(sqrtf(dx*dx + dy*dy));
    }
    #pragma unroll
    for (int off = 1; off < 64; off <<= 1) {
        const float w = __shfl_up(v, off, 64);
        if ((tid & 63) >= off) v += w;
    }
    if ((tid & 63) == 63) wsum[tid >> 6] = v;
    __syncthreads();
    if (tid < 16) {
        float x = wsum[tid];
        #pragma unroll
        for (int off = 1; off < 16; off <<= 1) {
            const float w = __shfl_up(x, off, 16);
            if (tid >= off) x += w;
        }
        wsum[tid] = x;
    }
    __syncthreads();
    const float incl = v + ((tid >= 64) ? wsum[(tid >> 6) - 1] : 0.f);

    if (tid == 0)       { skn[0] = 0.f; skn[NAUX] = 1e30f; g_kn[0] = 0.f; g_kn[1003] = 1e30f; }
    if (tid < NAUX - 1) { skn[tid+1] = incl; g_kn[tid+1] = incl; }
    __syncthreads();

    if (tid < CPN) {
        const int sg = tid + 1;
        const float t0 = skn[sg-1], t1 = skn[sg], t2 = skn[sg+1], t3 = skn[sg+2];
        const float A = t1 - t0, B = t2 - t1, C = t3 - t2;
        const float r01 = 1.0f / A;
        const float r12 = 1.0f / B;
        const float r23 = 1.0f / C;
        const float r02 = 1.0f / (A + B);
        const float r13 = 1.0f / (B + C);
        const float C3  = B + C;

        const float P0x = sax[sg-1], P0y = say[sg-1];
        const float P1x = sax[sg],   P1y = say[sg];
        const float P2x = sax[sg+1], P2y = say[sg+1];
        const float P3x = sax[sg+2], P3y = say[sg+2];

        const float L01_1x = (P1x - P0x) * r01, L01_1y = (P1y - P0y) * r01;
        const float L12_1x = (P2x - P1x) * r12, L12_1y = (P2y - P1y) * r12;
        const float L23_0x = ((B + C) * P2x - B * P3x) * r23;
        const float L23_0y = ((B + C) * P2y - B * P3y) * r23;
        const float L23_1x = (P3x - P2x) * r23, L23_1y = (P3y - P2y) * r23;

        const float Q012_0x = (B * P1x + A * P1x) * r02;
        const float Q012_0y = (B * P1y + A * P1y) * r02;
        const float Q012_1x = (B * L01_1x - P1x + A * L12_1x + P1x) * r02;
        const float Q012_1y = (B * L01_1y - P1y + A * L12_1y + P1y) * r02;
        const float Q012_2x = (L12_1x - L01_1x) * r02;
        const float Q012_2y = (L12_1y - L01_1y) * r02;

        const float Q123_0x = C3 * P1x * r13;
        const float Q123_0y = C3 * P1y * r13;
        const float Q123_1x = (C3 * L12_1x - P1x + L23_0x) * r13;
        const float Q123_1y = (C3 * L12_1y - P1y + L23_0y) * r13;
        const float Q123_2x = (L23_1x - L12_1x) * r13;
        const float Q123_2y = (L23_1y - L12_1y) * r13;

        const float k0x = B * Q012_0x * r12;
        const float k1x = (B * Q012_1x - Q012_0x + Q123_0x) * r12;
        const float k2x = (B * Q012_2x - Q012_1x + Q123_1x) * r12;
        const float k3x = (Q123_2x - Q012_2x) * r12;
        const float k0y = B * Q012_0y * r12;
        const float k1y = (B * Q012_1y - Q012_0y + Q123_0y) * r12;
        const float k2y = (B * Q012_2y - Q012_1y + Q123_1y) * r12;
        const float k3y = (Q123_2y - Q012_2y) * r12;

        uint4 r;
        r.x = pk2h(k0x, k0y);
        r.y = pk2h(k1x, k1y);
        r.z = pk2h(k2x, k2y);
        r.w = pk2h(k3x, k3y);
        g_rec[tid] = r;
    }
    __syncthreads();

    // bucket LUT: k0 (segment at bucket left edge), next-5-knot deltas, flag
    const float lo = skn[1];
    const float hi = skn[CPN + 1];
    const float w  = (hi - lo) / (float)NB;
    if (tid < NB) {
        const float bl = lo + (float)tid * w;
        int l = 0, h = NAUX;
        #pragma unroll
        for (int it = 0; it < 10; ++it) {
            const int mid = (l + h) >> 1;
            const bool c = (skn[mid] <= bl);
            l = c ? mid : l;
            h = c ? h : mid;
        }
        const int k0 = l < 1 ? 1 : (l > CPN ? CPN : l);
        const float t1_0 = skn[k0];

        unsigned short dh[5];
        float prev = t1_0;
        #pragma unroll
        for (int i = 1; i <= 5; ++i) {
            const float kn = (k0 + i <= CPN) ? skn[k0 + i] : 1e30f; // -> f16 65504 (RTZ)
            float delta = kn - prev;
            if (delta > 60000.0f) delta = 60000.0f;
            if (delta < 0.0f)     delta = 0.0f;
            dh[i-1] = (unsigned short)(pk2h(delta, 0.0f) & 0xFFFFu);
            prev = kn;
        }
        const unsigned int flag =
            ((k0 + 6 <= CPN) && (skn[k0 + 6] <= bl + w * 1.001f)) ? 0x8000u : 0u;

        uint4 e;
        e.x = __float_as_uint(t1_0);
        e.y = ((unsigned int)k0 | flag) | ((unsigned int)dh[0] << 16);
        e.z = (unsigned int)dh[1] | ((unsigned int)dh[2] << 16);
        e.w = (unsigned int)dh[3] | ((unsigned int)dh[4] << 16);
        g_lut[tid] = e;
    }
}

// ---------------------------------------------------------------------------
// Eval: R12 structure EXACTLY, except stores are nontemporal (full-line
// coalesced since R10: 16B/lane wave-contiguous). A/B probe for L2
// write-allocate pollution (R15).
// ---------------------------------------------------------------------------
__global__ __launch_bounds__(512, 8)
void spline_eval(const float* __restrict__ tq,
                 const float* __restrict__ g_kn,
                 const uint4* __restrict__ g_rec,
                 const uint4* __restrict__ g_lut,
                 float* __restrict__ out,   // n*2 floats
                 int n)
{
    __shared__ __align__(16) uint4 s_lut[NB];      // 16 KB
    __shared__ __align__(16) uint4 s_rec[CPN];     // 16 KB
    __shared__ __align__(16) float s_kn[1004];     //  4 KB (rare fallback only)
    const int tid = threadIdx.x;

    for (int i = tid; i < NB; i += 512)  s_lut[i] = g_lut[i];
    for (int i = tid; i < CPN; i += 512) s_rec[i] = g_rec[i];
    for (int i = tid; i < 251; i += 512) ((float4*)s_kn)[i] = ((const float4*)g_kn)[i];
    __syncthreads();

    const float lo    = s_kn[1];
    const float hi    = s_kn[CPN + 1];
    const float inv_w = (float)NB / (hi - lo);

    const int gid = blockIdx.x * 512 + tid;
    const int T   = gridDim.x * 512;     // total threads (524288)
    const int P   = n >> 1;              // query pairs (4194304)

    const float2* tq2 = (const float2*)tq;

    for (int p0 = gid; p0 < P; p0 += 4 * T) {
        const int p1 = p0 + T, p2 = p0 + 2 * T, p3 = p0 + 3 * T;
        const bool b1 = p1 < P, b2 = p2 < P, b3 = p3 < P;

        const float2 ta = tq2[p0];
        const float2 tb = b1 ? tq2[p1] : ta;
        const float2 tc = b2 ? tq2[p2] : ta;
        const float2 td = b3 ? tq2[p3] : ta;

        // ---- two groups of 4 queries, each fully phase-batched ----
        #pragma unroll
        for (int g = 0; g < 2; ++g) {
            float t0_, t1_, t2_, t3_;
            if (g == 0) { t0_ = ta.x; t1_ = ta.y; t2_ = tb.x; t3_ = tb.y; }
            else        { t0_ = tc.x; t1_ = tc.y; t2_ = td.x; t3_ = td.y; }
            const float tv[4] = {t0_, t1_, t2_, t3_};

            // phase 1: buckets + 4 independent LUT reads
            uint4 e[4];
            #pragma unroll
            for (int q = 0; q < 4; ++q) {
                int b = (int)((tv[q] - lo) * inv_w);
                b = b < 0 ? 0 : (b > NB - 1 ? NB - 1 : b);
                e[q] = s_lut[b];
            }

            // phase 2: branchless 5-delta select -> sg, u
            int   sg[4];
            float uu[4];
            #pragma unroll
            for (int q = 0; q < 4; ++q) {
                const float t = tv[q];
                float t1 = __uint_as_float(e[q].x);
                const unsigned int sgf = e[q].y & 0xFFFFu;
                int s = (int)(sgf & 0x7FFFu);
                const float c1 = t1 + h2f_hi(e[q].y);
                const float c2 = c1 + h2f_lo(e[q].z);
                const float c3 = c2 + h2f_hi(e[q].z);
                const float c4 = c3 + h2f_lo(e[q].w);
                const float c5 = c4 + h2f_hi(e[q].w);
                const bool g1 = t >= c1, g2 = t >= c2, g3 = t >= c3, g4 = t >= c4, g5 = t >= c5;
                s += (int)g1 + (int)g2 + (int)g3 + (int)g4 + (int)g5;
                t1 = g1 ? c1 : t1;
                t1 = g2 ? c2 : t1;
                t1 = g3 ? c3 : t1;
                t1 = g4 ? c4 : t1;
                t1 = g5 ? c5 : t1;
                if (__builtin_expect((sgf & 0x8000u) != 0 && g5, 0)) {   // rare walk
                    while (s < CPN && s_kn[s + 1] <= t) ++s;
                    t1 = s_kn[s];
                }
                sg[q] = s;
                uu[q] = t - t1;
            }

            // phase 3: 4 independent record reads
            uint4 r[4];
            #pragma unroll
            for (int q = 0; q < 4; ++q) r[q] = s_rec[sg[q] - 1];

            // phase 4: Horner + coalesced NT stores
            float rx[4], ry[4];
            #pragma unroll
            for (int q = 0; q < 4; ++q) {
                const float u = uu[q];
                rx[q] = fmaf(fmaf(fmaf(h2f_lo(r[q].w), u, h2f_lo(r[q].z)), u, h2f_lo(r[q].y)), u, h2f_lo(r[q].x));
                ry[q] = fmaf(fmaf(fmaf(h2f_hi(r[q].w), u, h2f_hi(r[q].z)), u, h2f_hi(r[q].y)), u, h2f_hi(r[q].x));
            }

            if (g == 0) {
                nt_store4(out + 4*p0, rx[0], ry[0], rx[1], ry[1]);
                if (b1) nt_store4(out + 4*p1, rx[2], ry[2], rx[3], ry[3]);
            } else {
                if (b2) nt_store4(out + 4*p2, rx[0], ry[0], rx[1], ry[1]);
                if (b3) nt_store4(out + 4*p3, rx[2], ry[2], rx[3], ry[3]);
            }
        }
    }

    // tail (n odd) — not hit for N=8388608
    if ((n & 1) && gid == 0) {
        const int q = n - 1;
        const float t = tq[q];
        int b = (int)((t - lo) * inv_w);
        b = b < 0 ? 0 : (b > NB - 1 ? NB - 1 : b);
        const uint4 e = s_lut[b];
        float t1 = __uint_as_float(e.x);
        const unsigned int sgf = e.y & 0xFFFFu;
        int s = (int)(sgf & 0x7FFFu);
        const float c1 = t1 + h2f_hi(e.y);
        const float c2 = c1 + h2f_lo(e.z);
        const float c3 = c2 + h2f_hi(e.z);
        const float c4 = c3 + h2f_lo(e.w);
        const float c5 = c4 + h2f_hi(e.w);
        const bool g1 = t >= c1, g2 = t >= c2, g3 = t >= c3, g4 = t >= c4, g5 = t >= c5;
        s += (int)g1 + (int)g2 + (int)g3 + (int)g4 + (int)g5;
        t1 = g1 ? c1 : t1; t1 = g2 ? c2 : t1; t1 = g3 ? c3 : t1;
        t1 = g4 ? c4 : t1; t1 = g5 ? c5 : t1;
        if ((sgf & 0x8000u) != 0 && g5) {
            while (s < CPN && s_kn[s + 1] <= t) ++s;
            t1 = s_kn[s];
        }
        const float u = t - t1;
        const uint4 r = s_rec[s - 1];
        out[2*q]     = fmaf(fmaf(fmaf(h2f_lo(r.w), u, h2f_lo(r.z)), u, h2f_lo(r.y)), u, h2f_lo(r.x));
        out[2*q + 1] = fmaf(fmaf(fmaf(h2f_hi(r.w), u, h2f_hi(r.z)), u, h2f_hi(r.y)), u, h2f_hi(r.x));
    }
}

extern "C" void kernel_launch(void* const* d_in, const int* in_sizes, int n_in,
                              void* d_out, int out_size, void* d_ws, size_t ws_size,
                              hipStream_t stream) {
    const float* cps = (const float*)d_in[0];
    const float* tq  = (const float*)d_in[1];
    float* out       = (float*)d_out;
    const int n      = in_sizes[1];

    // ws layout (bytes): [0,4096) knots f32 | [4096,20096) rec 16B x1000 | [20480,36864) LUT 16B x1024
    float* g_kn  = (float*)d_ws;
    uint4* g_rec = (uint4*)((char*)d_ws + 4096);
    uint4* g_lut = (uint4*)((char*)d_ws + 20480);

    spline_setup<<<1, 1024, 0, stream>>>(cps, g_kn, g_rec, g_lut);

    const int blocks = 1024;   // 4 blocks/CU x 256 CUs
    spline_eval<<<blocks, 512, 0, stream>>>(tq, g_kn, g_rec, g_lut, out, n);
}